// Round 9
// baseline (108.862 us; speedup 1.0000x reference)
//
#include <hip/hip_runtime.h>
#include <cmath>

namespace {
constexpr int Cc = 256, CKc = 32, CVc = 32, KKc = 9;
constexpr int Bc = 8, Hc = 128, Wc = 128, HWc = Hc * Wc;

typedef __attribute__((ext_vector_type(8))) short   s16x8;
typedef __attribute__((ext_vector_type(8))) __bf16  bf16x8;
typedef __attribute__((ext_vector_type(4))) float   f32x4;

__device__ inline unsigned short f2bf(float f) {   // RNE f32 -> bf16 bits
    union { float f; unsigned u; } v; v.f = f;
    unsigned u = v.u + 0x7fffu + ((v.u >> 16) & 1u);
    return (unsigned short)(u >> 16);
}
}

// ---- Kernel 1: k1 = relu(W_k1 x + b), v = W_v x + b  via bf16 MFMA ----
// Outputs PX-MAJOR bf16: k1pm/vpm [b][hw][32]. Block 0 also converts o_w -> bf16.
__global__ __launch_bounds__(256) void ns_k1v(
    const float* __restrict__ x,
    const float* __restrict__ k1_w, const float* __restrict__ k1_b,
    const float* __restrict__ v_w,  const float* __restrict__ v_b,
    const float* __restrict__ o_w,
    unsigned short* __restrict__ k1pm, unsigned short* __restrict__ vpm,
    unsigned short* __restrict__ owbf)
{
    constexpr int LP = 72;                      // row stride (shorts): 144 B
    __shared__ short w_bf[64][LP];              // chunk of W (64 o x 64 ch)
    __shared__ short x_bf[128][LP];             // chunk of X (128 px x 64 ch)

    const int tid = threadIdx.x;
    const int l   = tid & 63;
    const int li  = l & 15;
    const int lk  = l >> 4;
    const int wv  = __builtin_amdgcn_readfirstlane(tid >> 6);

    // one-time o_w -> bf16 (owbf consumed only by ns_fused, after this kernel ends)
    if (blockIdx.x == 0) {
        for (int i = tid * 4; i < Cc * CVc; i += 256 * 4) {
            const float4 f = *(const float4*)(o_w + i);
            const unsigned a = (unsigned)f2bf(f.x) | ((unsigned)f2bf(f.y) << 16);
            const unsigned c = (unsigned)f2bf(f.z) | ((unsigned)f2bf(f.w) << 16);
            *(uint2*)(owbf + i) = make_uint2(a, c);
        }
    }

    const int flat0 = blockIdx.x * 128;
    const int b  = flat0 / HWc;
    const int pp = flat0 - b * HWc;
    const float* xb = x + (size_t)b * Cc * HWc + pp;

    const int spx  = tid & 127;                 // X staging: pixel row
    const int schh = tid >> 7;
    const int so   = tid & 63;                  // W staging: output row
    const int swc0 = (tid >> 6) * 16;
    const float* wsrc = (so < 32) ? (k1_w + (size_t)so * Cc)
                                  : (v_w + (size_t)(so - 32) * Cc);

    f32x4 acc[8];
    const f32x4 zero = {0.f, 0.f, 0.f, 0.f};
#pragma unroll
    for (int i = 0; i < 8; ++i) acc[i] = zero;

    for (int c0 = 0; c0 < Cc; c0 += 64) {
        __syncthreads();
        {
            alignas(16) short tmp[16];
#pragma unroll
            for (int f = 0; f < 4; ++f) {
                const float4 fv = *(const float4*)(wsrc + c0 + swc0 + f * 4);
                tmp[f*4+0] = f2bf(fv.x); tmp[f*4+1] = f2bf(fv.y);
                tmp[f*4+2] = f2bf(fv.z); tmp[f*4+3] = f2bf(fv.w);
            }
            *(s16x8*)&w_bf[so][swc0]     = *(const s16x8*)&tmp[0];
            *(s16x8*)&w_bf[so][swc0 + 8] = *(const s16x8*)&tmp[8];
        }
#pragma unroll
        for (int u = 0; u < 8; ++u) {
            const int ch = (schh * 8 + u) * 4;
            const float e0 = xb[(size_t)(c0 + ch + 0) * HWc + spx];
            const float e1 = xb[(size_t)(c0 + ch + 1) * HWc + spx];
            const float e2 = xb[(size_t)(c0 + ch + 2) * HWc + spx];
            const float e3 = xb[(size_t)(c0 + ch + 3) * HWc + spx];
            const unsigned p01 = (unsigned)f2bf(e0) | ((unsigned)f2bf(e1) << 16);
            const unsigned p23 = (unsigned)f2bf(e2) | ((unsigned)f2bf(e3) << 16);
            *(uint2*)&x_bf[spx][ch] = make_uint2(p01, p23);
        }
        __syncthreads();

#pragma unroll
        for (int ks = 0; ks < 2; ++ks) {
            const s16x8 ar = *(const s16x8*)&w_bf[wv * 16 + li][ks * 32 + lk * 8];
            const bf16x8 af = __builtin_bit_cast(bf16x8, ar);
#pragma unroll
            for (int pt = 0; pt < 8; ++pt) {
                const s16x8 br = *(const s16x8*)&x_bf[pt * 16 + li][ks * 32 + lk * 8];
                acc[pt] = __builtin_amdgcn_mfma_f32_16x16x32_bf16(
                    af, __builtin_bit_cast(bf16x8, br), acc[pt], 0, 0, 0);
            }
        }
    }

    // ---- epilogue: bias (+relu for k1), bf16 px-major store (8 B per px) ----
    const bool is_k = wv < 2;
    const int obase = wv * 16 + lk * 4;
    const int chq = is_k ? obase : obase - 32;  // channel quad within [0,32)
    float bias[4];
#pragma unroll
    for (int r = 0; r < 4; ++r)
        bias[r] = is_k ? k1_b[obase + r] : v_b[obase + r - 32];
    unsigned short* dstb = is_k ? k1pm : vpm;

#pragma unroll
    for (int pt = 0; pt < 8; ++pt) {
        const size_t row = (size_t)b * HWc + pp + pt * 16 + li;
        float v0 = acc[pt][0] + bias[0], v1 = acc[pt][1] + bias[1];
        float v2 = acc[pt][2] + bias[2], v3 = acc[pt][3] + bias[3];
        if (is_k) {
            v0 = fmaxf(v0, 0.f); v1 = fmaxf(v1, 0.f);
            v2 = fmaxf(v2, 0.f); v3 = fmaxf(v3, 0.f);
        }
        const unsigned p01 = (unsigned)f2bf(v0) | ((unsigned)f2bf(v1) << 16);
        const unsigned p23 = (unsigned)f2bf(v2) | ((unsigned)f2bf(v3) << 16);
        *(uint2*)(dstb + row * 32 + chq) = make_uint2(p01, p23);
    }
}

// -- Kernel 2 (fused): dw3x3 + 1x1->9 + softmax + unfold-agg on px-major bf16,
//    then out conv via bf16 MFMA (A=y so D is px-major) + bias + residual. --
__global__ __launch_bounds__(256) void ns_fused(
    const float* __restrict__ x,
    const unsigned short* __restrict__ k1pm,
    const unsigned short* __restrict__ vpm,
    const float* __restrict__ dw_w, const float* __restrict__ dw_b,
    const float* __restrict__ k3_w, const float* __restrict__ k3_b,
    const unsigned short* __restrict__ owbf, const float* __restrict__ o_b,
    float* __restrict__ out)
{
    constexpr int PX = 256;
    constexpr int WPAD = 40;                    // 80 B rows, 16B-aligned
    __shared__ short y_lds[PX][WPAD];           // 20 KB
    __shared__ float dwt[KKc][CKc];
    __shared__ float k3s[KKc][CKc];
    __shared__ float dwbs[CKc];
    __shared__ float k3bs[KKc];

    const int tid = threadIdx.x;
    for (int idx = tid; idx < CKc * KKc; idx += 256) {
        const int ck = idx / KKc, kk = idx - ck * KKc;
        dwt[kk][ck] = dw_w[idx];
        ((float*)k3s)[idx] = k3_w[idx];
    }
    if (tid < CKc) dwbs[tid] = dw_b[tid];
    if (tid < KKc) k3bs[tid] = k3_b[tid];
    __syncthreads();

    const int flat0 = blockIdx.x * PX;
    const int b  = flat0 / HWc;
    const int p0 = flat0 - b * HWc;
    const int p  = p0 + tid;
    const int h  = p / Wc;
    const int w  = p - h * Wc;

    const unsigned short* k1b = k1pm + (size_t)b * HWc * 32;
    const unsigned short* vb  = vpm  + (size_t)b * HWc * 32;

    // ---- depthwise 3x3 (px-major bf16 reads: 4x dwordx4 per neighbor) ----
    float t[CKc];
#pragma unroll
    for (int ck = 0; ck < CKc; ++ck) t[ck] = dwbs[ck];
#pragma unroll
    for (int i = 0; i < 3; ++i) {
        const int hh = h + i - 1;
#pragma unroll
        for (int j = 0; j < 3; ++j) {
            const int ww = w + j - 1;
            if (hh < 0 || hh >= Hc || ww < 0 || ww >= Wc) continue;
            const unsigned short* kr = k1b + (size_t)(hh * Wc + ww) * 32;
            const int ij = i * 3 + j;
#pragma unroll
            for (int qv = 0; qv < 4; ++qv) {
                const bf16x8 kv = __builtin_bit_cast(bf16x8, *(const s16x8*)(kr + qv * 8));
#pragma unroll
                for (int e = 0; e < 8; ++e)
                    t[qv * 8 + e] = fmaf((float)kv[e], dwt[ij][qv * 8 + e], t[qv * 8 + e]);
            }
        }
    }

    // ---- 1x1 CK->9 + softmax ----
    float logit[KKc];
#pragma unroll
    for (int kk = 0; kk < KKc; ++kk) {
        float a = k3bs[kk];
#pragma unroll
        for (int ck = 0; ck < CKc; ++ck)
            a = fmaf(k3s[kk][ck], t[ck], a);
        logit[kk] = a;
    }
    float m = logit[0];
#pragma unroll
    for (int kk = 1; kk < KKc; ++kk) m = fmaxf(m, logit[kk]);
    float s = 0.f;
#pragma unroll
    for (int kk = 0; kk < KKc; ++kk) { logit[kk] = expf(logit[kk] - m); s += logit[kk]; }
    const float inv = 1.f / s;
#pragma unroll
    for (int kk = 0; kk < KKc; ++kk) logit[kk] *= inv;

    // ---- unfold-aggregate (px-major bf16 v) ----
    float yv[CVc];
#pragma unroll
    for (int cv = 0; cv < CVc; ++cv) yv[cv] = 0.f;
#pragma unroll
    for (int i = 0; i < 3; ++i) {
        const int hh = h + i - 1;
#pragma unroll
        for (int j = 0; j < 3; ++j) {
            const int ww = w + j - 1;
            if (hh < 0 || hh >= Hc || ww < 0 || ww >= Wc) continue;
            const unsigned short* vr = vb + (size_t)(hh * Wc + ww) * 32;
            const float wv = logit[i * 3 + j];
#pragma unroll
            for (int qv = 0; qv < 4; ++qv) {
                const bf16x8 vv = __builtin_bit_cast(bf16x8, *(const s16x8*)(vr + qv * 8));
#pragma unroll
                for (int e = 0; e < 8; ++e)
                    yv[qv * 8 + e] = fmaf(wv, (float)vv[e], yv[qv * 8 + e]);
            }
        }
    }

    // y -> LDS bf16 [px][cv]
    {
        alignas(16) short ybf[CVc];
#pragma unroll
        for (int cv = 0; cv < CVc; ++cv) ybf[cv] = (short)f2bf(yv[cv]);
#pragma unroll
        for (int cq = 0; cq < 4; ++cq)
            *(float4*)&y_lds[tid][cq * 8] = *(const float4*)&ybf[cq * 8];
    }
    __syncthreads();

    // ---- out conv via MFMA, operand-swapped: D[m=px][n=och].
    //      lane: och = ot*16 + (l&15); px = p0 + pt*16 + (l>>4)*4 + r  (r=0..3)
    //      -> float4 x-load / float4 out-store per MFMA. ----
    const int wvv = tid >> 6;
    const int l  = tid & 63;
    const int li = l & 15;
    const int lk = l >> 4;

    const float* xb0 = x + (size_t)b * Cc * HWc;
    float* ob0 = out + (size_t)b * Cc * HWc;

#pragma unroll
    for (int i = 0; i < 4; ++i) {
        const int ot = wvv * 4 + i;
        const int och = ot * 16 + li;
        const s16x8 wr8 = *(const s16x8*)(owbf + (size_t)och * 32 + lk * 8);
        const bf16x8 wfrag = __builtin_bit_cast(bf16x8, wr8);  // B[k=cv][n=och]
        const float bias = o_b[och];
        const float* xrow = xb0 + (size_t)och * HWc;
        float* orow = ob0 + (size_t)och * HWc;
#pragma unroll
        for (int pt = 0; pt < 16; ++pt) {
            const s16x8 yr8 = *(const s16x8*)&y_lds[pt * 16 + li][lk * 8];
            const bf16x8 yfrag = __builtin_bit_cast(bf16x8, yr8); // A[m=px][k=cv]
            f32x4 acc = {0.f, 0.f, 0.f, 0.f};
            acc = __builtin_amdgcn_mfma_f32_16x16x32_bf16(yfrag, wfrag, acc, 0, 0, 0);
            const int px0 = p0 + pt * 16 + lk * 4;
            const float4 xv = *(const float4*)(xrow + px0);
            float4 ov;
            ov.x = xv.x + acc[0] + bias;
            ov.y = xv.y + acc[1] + bias;
            ov.z = xv.z + acc[2] + bias;
            ov.w = xv.w + acc[3] + bias;
            *(float4*)(orow + px0) = ov;
        }
    }
}

extern "C" void kernel_launch(void* const* d_in, const int* in_sizes, int n_in,
                              void* d_out, int out_size, void* d_ws, size_t ws_size,
                              hipStream_t stream)
{
    const float* x    = (const float*)d_in[0];
    const float* k1_w = (const float*)d_in[1];
    const float* k1_b = (const float*)d_in[2];
    const float* dw_w = (const float*)d_in[3];
    const float* dw_b = (const float*)d_in[4];
    const float* k3_w = (const float*)d_in[5];
    const float* k3_b = (const float*)d_in[6];
    const float* v_w  = (const float*)d_in[7];
    const float* v_b  = (const float*)d_in[8];
    const float* o_w  = (const float*)d_in[9];
    const float* o_b  = (const float*)d_in[10];
    float* out = (float*)d_out;

    // workspace: k1pm (8.4 MB) | vpm (8.4 MB) | owbf (16 KB), all bf16
    unsigned short* k1pm = (unsigned short*)d_ws;
    unsigned short* vpm  = k1pm + (size_t)Bc * HWc * 32;
    unsigned short* owbf = vpm  + (size_t)Bc * HWc * 32;

    const int npx = Bc * HWc;                   // 131072

    ns_k1v <<<dim3(npx / 128), dim3(256), 0, stream>>>(x, k1_w, k1_b, v_w, v_b, o_w,
                                                       k1pm, vpm, owbf);
    ns_fused<<<dim3(npx / 256), dim3(256), 0, stream>>>(x, k1pm, vpm, dw_w, dw_b,
                                                        k3_w, k3_b, owbf, o_b, out);
}

// Round 10
// 100.096 us; speedup vs baseline: 1.0876x; 1.0876x over previous
//
#include <hip/hip_runtime.h>
#include <cmath>

namespace {
constexpr int Cc = 256, CKc = 32, CVc = 32, KKc = 9;
constexpr int Bc = 8, Hc = 128, Wc = 128, HWc = Hc * Wc;

typedef __attribute__((ext_vector_type(8))) short   s16x8;
typedef __attribute__((ext_vector_type(8))) __bf16  bf16x8;
typedef __attribute__((ext_vector_type(4))) float   f32x4;

__device__ inline unsigned short f2bf(float f) {   // RNE f32 -> bf16 bits
    union { float f; unsigned u; } v; v.f = f;
    unsigned u = v.u + 0x7fffu + ((v.u >> 16) & 1u);
    return (unsigned short)(u >> 16);
}
}

// ---- Kernel 1: k1 = relu(W_k1 x + b), v = W_v x + b  via bf16 MFMA ----
// Outputs PX-MAJOR bf16: k1pm/vpm [b][hw][32]. Block 0 also converts o_w -> bf16.
__global__ __launch_bounds__(256) void ns_k1v(
    const float* __restrict__ x,
    const float* __restrict__ k1_w, const float* __restrict__ k1_b,
    const float* __restrict__ v_w,  const float* __restrict__ v_b,
    const float* __restrict__ o_w,
    unsigned short* __restrict__ k1pm, unsigned short* __restrict__ vpm,
    unsigned short* __restrict__ owbf)
{
    constexpr int LP = 72;                      // row stride (shorts): 144 B
    __shared__ short w_bf[64][LP];              // chunk of W (64 o x 64 ch)
    __shared__ short x_bf[128][LP];             // chunk of X (128 px x 64 ch)

    const int tid = threadIdx.x;
    const int l   = tid & 63;
    const int li  = l & 15;
    const int lk  = l >> 4;
    const int wv  = __builtin_amdgcn_readfirstlane(tid >> 6);

    // one-time o_w -> bf16 (owbf consumed only by ns_fused, after this kernel ends)
    if (blockIdx.x == 0) {
        for (int i = tid * 4; i < Cc * CVc; i += 256 * 4) {
            const float4 f = *(const float4*)(o_w + i);
            const unsigned a = (unsigned)f2bf(f.x) | ((unsigned)f2bf(f.y) << 16);
            const unsigned c = (unsigned)f2bf(f.z) | ((unsigned)f2bf(f.w) << 16);
            *(uint2*)(owbf + i) = make_uint2(a, c);
        }
    }

    const int flat0 = blockIdx.x * 128;
    const int b  = flat0 / HWc;
    const int pp = flat0 - b * HWc;
    const float* xb = x + (size_t)b * Cc * HWc + pp;

    const int spx  = tid & 127;                 // X staging: pixel row
    const int schh = tid >> 7;
    const int so   = tid & 63;                  // W staging: output row
    const int swc0 = (tid >> 6) * 16;
    const float* wsrc = (so < 32) ? (k1_w + (size_t)so * Cc)
                                  : (v_w + (size_t)(so - 32) * Cc);

    f32x4 acc[8];
    const f32x4 zero = {0.f, 0.f, 0.f, 0.f};
#pragma unroll
    for (int i = 0; i < 8; ++i) acc[i] = zero;

    for (int c0 = 0; c0 < Cc; c0 += 64) {
        __syncthreads();
        {
            alignas(16) short tmp[16];
#pragma unroll
            for (int f = 0; f < 4; ++f) {
                const float4 fv = *(const float4*)(wsrc + c0 + swc0 + f * 4);
                tmp[f*4+0] = f2bf(fv.x); tmp[f*4+1] = f2bf(fv.y);
                tmp[f*4+2] = f2bf(fv.z); tmp[f*4+3] = f2bf(fv.w);
            }
            *(s16x8*)&w_bf[so][swc0]     = *(const s16x8*)&tmp[0];
            *(s16x8*)&w_bf[so][swc0 + 8] = *(const s16x8*)&tmp[8];
        }
#pragma unroll
        for (int u = 0; u < 8; ++u) {
            const int ch = (schh * 8 + u) * 4;
            const float e0 = xb[(size_t)(c0 + ch + 0) * HWc + spx];
            const float e1 = xb[(size_t)(c0 + ch + 1) * HWc + spx];
            const float e2 = xb[(size_t)(c0 + ch + 2) * HWc + spx];
            const float e3 = xb[(size_t)(c0 + ch + 3) * HWc + spx];
            const unsigned p01 = (unsigned)f2bf(e0) | ((unsigned)f2bf(e1) << 16);
            const unsigned p23 = (unsigned)f2bf(e2) | ((unsigned)f2bf(e3) << 16);
            *(uint2*)&x_bf[spx][ch] = make_uint2(p01, p23);
        }
        __syncthreads();

#pragma unroll
        for (int ks = 0; ks < 2; ++ks) {
            const s16x8 ar = *(const s16x8*)&w_bf[wv * 16 + li][ks * 32 + lk * 8];
            const bf16x8 af = __builtin_bit_cast(bf16x8, ar);
#pragma unroll
            for (int pt = 0; pt < 8; ++pt) {
                const s16x8 br = *(const s16x8*)&x_bf[pt * 16 + li][ks * 32 + lk * 8];
                acc[pt] = __builtin_amdgcn_mfma_f32_16x16x32_bf16(
                    af, __builtin_bit_cast(bf16x8, br), acc[pt], 0, 0, 0);
            }
        }
    }

    // ---- epilogue: bias (+relu for k1), bf16 px-major store (8 B per px) ----
    const bool is_k = wv < 2;
    const int obase = wv * 16 + lk * 4;
    const int chq = is_k ? obase : obase - 32;  // channel quad within [0,32)
    float bias[4];
#pragma unroll
    for (int r = 0; r < 4; ++r)
        bias[r] = is_k ? k1_b[obase + r] : v_b[obase + r - 32];
    unsigned short* dstb = is_k ? k1pm : vpm;

#pragma unroll
    for (int pt = 0; pt < 8; ++pt) {
        const size_t row = (size_t)b * HWc + pp + pt * 16 + li;
        float v0 = acc[pt][0] + bias[0], v1 = acc[pt][1] + bias[1];
        float v2 = acc[pt][2] + bias[2], v3 = acc[pt][3] + bias[3];
        if (is_k) {
            v0 = fmaxf(v0, 0.f); v1 = fmaxf(v1, 0.f);
            v2 = fmaxf(v2, 0.f); v3 = fmaxf(v3, 0.f);
        }
        const unsigned p01 = (unsigned)f2bf(v0) | ((unsigned)f2bf(v1) << 16);
        const unsigned p23 = (unsigned)f2bf(v2) | ((unsigned)f2bf(v3) << 16);
        *(uint2*)(dstb + row * 32 + chq) = make_uint2(p01, p23);
    }
}

// -- Kernel 2 (fused): 512 threads / 256 px. 2 threads per pixel (channel halves)
//    for dw3x3 + 1x1->9 (partials via LDS) + softmax + unfold-agg, then out conv
//    via bf16 MFMA (8 waves x 2 o-tiles) + bias + residual. --
__global__ __launch_bounds__(512, 4) void ns_fused(
    const float* __restrict__ x,
    const unsigned short* __restrict__ k1pm,
    const unsigned short* __restrict__ vpm,
    const float* __restrict__ dw_w, const float* __restrict__ dw_b,
    const float* __restrict__ k3_w, const float* __restrict__ k3_b,
    const unsigned short* __restrict__ owbf, const float* __restrict__ o_b,
    float* __restrict__ out)
{
    constexpr int PX = 256;
    constexpr int WPAD = 40;                    // 80 B rows, 16B-aligned
    __shared__ short y_lds[PX][WPAD];           // 20 KB
    __shared__ float plds[2][KKc][PX];          // 18 KB partial logits (transposed)
    __shared__ float dwt[KKc][CKc];
    __shared__ float k3s[KKc][CKc];
    __shared__ float dwbs[CKc];
    __shared__ float k3bs[KKc];

    const int tid = threadIdx.x;
    if (tid < CKc * KKc) {
        const int ck = tid / KKc, kk = tid - ck * KKc;
        dwt[kk][ck] = dw_w[tid];
        ((float*)k3s)[tid] = k3_w[tid];
    }
    if (tid < CKc) dwbs[tid] = dw_b[tid];
    if (tid < KKc) k3bs[tid] = k3_b[tid];
    __syncthreads();

    const int pxi  = tid & 255;                 // pixel within block
    const int half = tid >> 8;                  // channel half: [half*16, half*16+16)
    const int cb   = half * 16;                 // channel base

    const int flat0 = blockIdx.x * PX;
    const int b  = flat0 / HWc;
    const int p0 = flat0 - b * HWc;
    const int p  = p0 + pxi;
    const int h  = p / Wc;
    const int w  = p - h * Wc;

    const unsigned short* k1b = k1pm + (size_t)b * HWc * 32;
    const unsigned short* vb  = vpm  + (size_t)b * HWc * 32;

    // ---- depthwise 3x3, own 16 channels (2x dwordx4 per neighbor) ----
    float t[16];
#pragma unroll
    for (int e = 0; e < 16; ++e) t[e] = dwbs[cb + e];
#pragma unroll
    for (int i = 0; i < 3; ++i) {
        const int hh = h + i - 1;
#pragma unroll
        for (int j = 0; j < 3; ++j) {
            const int ww = w + j - 1;
            if (hh < 0 || hh >= Hc || ww < 0 || ww >= Wc) continue;
            const unsigned short* kr = k1b + (size_t)(hh * Wc + ww) * 32 + cb;
            const int ij = i * 3 + j;
#pragma unroll
            for (int qv = 0; qv < 2; ++qv) {
                const bf16x8 kv = __builtin_bit_cast(bf16x8, *(const s16x8*)(kr + qv * 8));
#pragma unroll
                for (int e = 0; e < 8; ++e)
                    t[qv * 8 + e] = fmaf((float)kv[e], dwt[ij][cb + qv * 8 + e],
                                         t[qv * 8 + e]);
            }
        }
    }

    // ---- partial 1x1 CK->9 over own 16 ch; exchange via LDS ----
#pragma unroll
    for (int kk = 0; kk < KKc; ++kk) {
        float a = (half == 0) ? k3bs[kk] : 0.f;
#pragma unroll
        for (int e = 0; e < 16; ++e)
            a = fmaf(k3s[kk][cb + e], t[e], a);
        plds[half][kk][pxi] = a;
    }
    __syncthreads();

    float logit[KKc];
#pragma unroll
    for (int kk = 0; kk < KKc; ++kk)
        logit[kk] = plds[0][kk][pxi] + plds[1][kk][pxi];

    float m = logit[0];
#pragma unroll
    for (int kk = 1; kk < KKc; ++kk) m = fmaxf(m, logit[kk]);
    float s = 0.f;
#pragma unroll
    for (int kk = 0; kk < KKc; ++kk) { logit[kk] = expf(logit[kk] - m); s += logit[kk]; }
    const float inv = 1.f / s;
#pragma unroll
    for (int kk = 0; kk < KKc; ++kk) logit[kk] *= inv;

    // ---- unfold-aggregate, own 16 v-channels ----
    float yv[16];
#pragma unroll
    for (int e = 0; e < 16; ++e) yv[e] = 0.f;
#pragma unroll
    for (int i = 0; i < 3; ++i) {
        const int hh = h + i - 1;
#pragma unroll
        for (int j = 0; j < 3; ++j) {
            const int ww = w + j - 1;
            if (hh < 0 || hh >= Hc || ww < 0 || ww >= Wc) continue;
            const unsigned short* vr = vb + (size_t)(hh * Wc + ww) * 32 + cb;
            const float wv = logit[i * 3 + j];
#pragma unroll
            for (int qv = 0; qv < 2; ++qv) {
                const bf16x8 vv = __builtin_bit_cast(bf16x8, *(const s16x8*)(vr + qv * 8));
#pragma unroll
                for (int e = 0; e < 8; ++e)
                    yv[qv * 8 + e] = fmaf(wv, (float)vv[e], yv[qv * 8 + e]);
            }
        }
    }

    // y -> LDS bf16 [px][cv] (own half: 32 B = 2x float4)
    {
        alignas(16) short ybf[16];
#pragma unroll
        for (int e = 0; e < 16; ++e) ybf[e] = (short)f2bf(yv[e]);
        *(float4*)&y_lds[pxi][cb]     = *(const float4*)&ybf[0];
        *(float4*)&y_lds[pxi][cb + 8] = *(const float4*)&ybf[8];
    }
    __syncthreads();

    // ---- out conv via MFMA, D[m=px][n=och]: 8 waves x 2 o-tiles ----
    const int wvv = tid >> 6;                   // 0..7
    const int l  = tid & 63;
    const int li = l & 15;
    const int lk = l >> 4;

    const float* xb0 = x + (size_t)b * Cc * HWc;
    float* ob0 = out + (size_t)b * Cc * HWc;

#pragma unroll
    for (int i = 0; i < 2; ++i) {
        const int ot = wvv * 2 + i;
        const int och = ot * 16 + li;
        const s16x8 wr8 = *(const s16x8*)(owbf + (size_t)och * 32 + lk * 8);
        const bf16x8 wfrag = __builtin_bit_cast(bf16x8, wr8);  // B[k=cv][n=och]
        const float bias = o_b[och];
        const float* xrow = xb0 + (size_t)och * HWc;
        float* orow = ob0 + (size_t)och * HWc;
#pragma unroll
        for (int pt = 0; pt < 16; ++pt) {
            const s16x8 yr8 = *(const s16x8*)&y_lds[pt * 16 + li][lk * 8];
            const bf16x8 yfrag = __builtin_bit_cast(bf16x8, yr8); // A[m=px][k=cv]
            f32x4 acc = {0.f, 0.f, 0.f, 0.f};
            acc = __builtin_amdgcn_mfma_f32_16x16x32_bf16(yfrag, wfrag, acc, 0, 0, 0);
            const int px0 = p0 + pt * 16 + lk * 4;
            const float4 xv = *(const float4*)(xrow + px0);
            float4 ov;
            ov.x = xv.x + acc[0] + bias;
            ov.y = xv.y + acc[1] + bias;
            ov.z = xv.z + acc[2] + bias;
            ov.w = xv.w + acc[3] + bias;
            *(float4*)(orow + px0) = ov;
        }
    }
}

extern "C" void kernel_launch(void* const* d_in, const int* in_sizes, int n_in,
                              void* d_out, int out_size, void* d_ws, size_t ws_size,
                              hipStream_t stream)
{
    const float* x    = (const float*)d_in[0];
    const float* k1_w = (const float*)d_in[1];
    const float* k1_b = (const float*)d_in[2];
    const float* dw_w = (const float*)d_in[3];
    const float* dw_b = (const float*)d_in[4];
    const float* k3_w = (const float*)d_in[5];
    const float* k3_b = (const float*)d_in[6];
    const float* v_w  = (const float*)d_in[7];
    const float* v_b  = (const float*)d_in[8];
    const float* o_w  = (const float*)d_in[9];
    const float* o_b  = (const float*)d_in[10];
    float* out = (float*)d_out;

    // workspace: k1pm (8.4 MB) | vpm (8.4 MB) | owbf (16 KB), all bf16
    unsigned short* k1pm = (unsigned short*)d_ws;
    unsigned short* vpm  = k1pm + (size_t)Bc * HWc * 32;
    unsigned short* owbf = vpm  + (size_t)Bc * HWc * 32;

    const int npx = Bc * HWc;                   // 131072

    ns_k1v <<<dim3(npx / 128), dim3(256), 0, stream>>>(x, k1_w, k1_b, v_w, v_b, o_w,
                                                       k1pm, vpm, owbf);
    ns_fused<<<dim3(npx / 256), dim3(512), 0, stream>>>(x, k1pm, vpm, dw_w, dw_b,
                                                        k3_w, k3_b, owbf, o_b, out);
}